// Round 24
// baseline (38.830 us; speedup 1.0000x reference)
//
#include <hip/hip_runtime.h>
#include <hip/hip_bf16.h>
#include <hip/hip_fp16.h>

#define N1   15996
#define N2   5328
#define NG2  5584
#define NJ   100
#define CLS  10
#define NMC  96      // K chunks: 24 per feature channel
#define MCH  74      // 1776 = 24*74
#define PAIRS 37
#define KROW 52      // LDS row stride in u32 (= 104 f16)
#define BT   32      // batch tile (8 tiles -> grid 768)
#define LDSF 7740    // 4B words: W1b 5824 + gA 1664 + g2w 252; T(3232) overlays

#define OFF_GA  5824     // u32: gA  [32*52]
#define OFF_G2W 7488     // f32: g2w [252]

typedef _Float16 h2v  __attribute__((ext_vector_type(2)));
typedef _Float16 f16x8 __attribute__((ext_vector_type(8)));
typedef float    f32x4 __attribute__((ext_vector_type(4)));

static __device__ __forceinline__ unsigned packh2(float a, float b) {
    union { h2v v; unsigned u; } U;
    U.v[0] = (_Float16)a; U.v[1] = (_Float16)b;
    return U.u;
}

// ---- KA: prep (conv1+dil1+conv2+dil2) once, 22 blocks (proven R13) ----
__global__ __launch_bounds__(256)
void ka_prep(const float* __restrict__ x,  const float* __restrict__ w1,
             const float* __restrict__ b1, const float* __restrict__ t1,
             const float* __restrict__ w2, const float* __restrict__ b2,
             const float* __restrict__ t2, float* __restrict__ g2)
{
    __shared__ float Y1[804];
    __shared__ float G [800];
    __shared__ float Y2[264];
    const int tid = threadIdx.x;
    const int bid = blockIdx.x;

    int c, p0, cnt;
    if (bid < 21) { c = 0; p0 = bid * 256; cnt = (p0 + 256 <= N2) ? 256 : (N2 - p0); }
    else          { c = 1; p0 = 0;         cnt = 256; }

    const int q0 = (p0 - 3 > 0) ? p0 - 3 : 0;
    const int q1 = (p0 + cnt - 1 + 3 < N2 - 1) ? p0 + cnt - 1 + 3 : N2 - 1;
    const int nq = q1 - q0 + 1;
    const int g0 = 3 * q0, g1 = 3 * q1 + 13;
    const int ng = g1 - g0 + 1;
    const int h0 = (g0 - 3 > 0) ? g0 - 3 : 0;
    const int h1 = (g1 + 3 < N1 - 1) ? g1 + 3 : N1 - 1;
    const int nh = h1 - h0 + 1;

    for (int idx = tid; idx < nh; idx += 256) {
        const int n = h0 + idx;
        float acc = b1[0];
        #pragma unroll
        for (int k = 0; k < 5; ++k) acc += x[n + k] * w1[k];
        Y1[idx] = fmaxf(acc, 0.f);
    }
    __syncthreads();
    {
        const float it1 = 1.f / (4.f * t1[0]);
        for (int idx = tid; idx < ng; idx += 256) {
            const int n = g0 + idx;
            float m = -INFINITY;
            #pragma unroll
            for (int d = 0; d < 7; ++d) {
                int p = n + d - 3;
                if ((unsigned)p < (unsigned)N1) {
                    float z = (float)(d - 3);
                    m = fmaxf(m, Y1[p - h0] - z * z * it1);
                }
            }
            G[idx] = m;
        }
    }
    __syncthreads();
    for (int idx = tid; idx < nq; idx += 256) {
        const int q = q0 + idx;
        float acc = b2[c];
        #pragma unroll
        for (int k = 0; k < 5; ++k) {
            #pragma unroll
            for (int i = 0; i < 2; ++i)
                acc += G[i + 3 * (q + k) - g0] * w2[(c * 2 + i) * 5 + k];
        }
        Y2[idx] = fmaxf(acc, 0.f);
    }
    __syncthreads();
    {
        const float it2 = 1.f / (4.f * t2[c]);
        for (int idx = tid; idx < cnt; idx += 256) {
            const int p = p0 + idx;
            float m = -INFINITY;
            #pragma unroll
            for (int d = 0; d < 7; ++d) {
                int q = p + d - 3;
                if ((unsigned)q < (unsigned)N2) {
                    float z = (float)(d - 3);
                    m = fmaxf(m, Y2[q - q0] - z * z * it2);
                }
            }
            g2[c * N2 + p] = m;
        }
    }
}

// ---- KB: fc1 MFMA, batch-tile 32, grid 768 (occupancy ~3 blocks/CU) ----
__global__ __launch_bounds__(256)
void kb_fc1(const float* __restrict__ g2, const float* __restrict__ W1,
            float* __restrict__ part)
{
    __shared__ float LDS[LDSF];              // 31 KB
    unsigned* W1b = (unsigned*)LDS;          // [112][52] u32 = f16[112][104]
    unsigned* gAu = (unsigned*)LDS + OFF_GA; // [32][52]
    float* g2w = LDS + OFF_G2W;              // [252]
    const int tid = threadIdx.x;
    const int bt  = blockIdx.x / NMC;        // 0..7
    const int mc  = blockIdx.x % NMC;        // 0..95
    const int c   = mc / 24;
    const int k0  = (mc % 24) * MCH;
    const int base = bt * BT + c + 3 * k0;   // <= 5333; max used = base+250 <= 5583

    for (int idx = tid; idx < NJ * PAIRS; idx += 256) {
        const int j = idx / PAIRS, p = idx % PAIRS;
        const float2 r = *reinterpret_cast<const float2*>(
            W1 + (size_t)j * 7104 + c * 1776 + k0 + 2 * p);
        W1b[j * KROW + p] = packh2(r.x, r.y);
    }
    for (int idx = tid; idx < NJ * 15; idx += 256) {          // K pad
        const int j = idx / 15, p = 37 + idx % 15;
        W1b[j * KROW + p] = 0u;
    }
    for (int idx = tid; idx < 12 * KROW; idx += 256)          // N pad
        W1b[(NJ + idx / KROW) * KROW + (idx % KROW)] = 0u;
    for (int i = tid; i < 252; i += 256) {
        const int gi = base + i;
        g2w[i] = (gi < NG2) ? g2[gi] : 0.f;
    }
    __syncthreads();

    // A operand: gA[b][k] = f16(g2w[b + 3k]), K padded 37..51
    for (int idx = tid; idx < BT * PAIRS; idx += 256) {
        const int b = idx / PAIRS, p = idx % PAIRS;
        gAu[b * KROW + p] = packh2(g2w[b + 6 * p], g2w[b + 6 * p + 3]);
    }
    for (int idx = tid; idx < BT * 15; idx += 256) {
        const int b = idx / 15, p = 37 + idx % 15;
        gAu[b * KROW + p] = 0u;
    }
    __syncthreads();

    // wave w: mt = w>>1 (16-row M tile), nt in [nt0, nt0+ntc)
    const int w  = tid >> 6, l = tid & 63;
    const int lr = l & 15, lg = l >> 4;
    const int mt  = w >> 1;
    const int nt0 = (w & 1) * 4;
    const int ntc = (w & 1) ? 3 : 4;
    f32x4 acc[4];
    #pragma unroll
    for (int i = 0; i < 4; ++i) acc[i] = (f32x4){0.f, 0.f, 0.f, 0.f};

    union FU { uint4 u; f16x8 h; };
    #pragma unroll
    for (int ks = 0; ks < 3; ++ks) {
        const int kb = ks * 16 + lg * 4;
        FU a, bfr[4];
        a.u = *reinterpret_cast<const uint4*>(gAu + (mt * 16 + lr) * KROW + kb);
        for (int ni = 0; ni < ntc; ++ni)
            bfr[ni].u = *reinterpret_cast<const uint4*>(W1b + ((nt0 + ni) * 16 + lr) * KROW + kb);
        for (int ni = 0; ni < ntc; ++ni)
            acc[ni] = __builtin_amdgcn_mfma_f32_16x16x32_f16(a.h, bfr[ni].h, acc[ni], 0, 0, 0);
    }
    __syncthreads();

    float* T = LDS;    // [32][101] padded
    for (int ni = 0; ni < ntc; ++ni)
        #pragma unroll
        for (int r = 0; r < 4; ++r) {
            const int brow = mt * 16 + lg * 4 + r;
            const int j    = (nt0 + ni) * 16 + lr;
            if (j < NJ) T[brow * 101 + j] = acc[ni][r];
        }
    __syncthreads();

    for (int idx = tid; idx < BT * NJ; idx += 256) {
        const int bl = idx / NJ, j = idx - bl * NJ;
        part[((size_t)(bt * BT + bl) * NMC + mc) * NJ + j] = T[bl * 101 + j];
    }
}

// ---- KC: reduce + fc2 + log_softmax; 512 threads, float4 staging ----
__global__ __launch_bounds__(512)
void kc_out(const float* __restrict__ part, const float* __restrict__ fb1,
            const float* __restrict__ W2,  const float* __restrict__ fb2,
            float* __restrict__ out)
{
    __shared__ float S[NMC * NJ];
    __shared__ float a1s[NJ];
    __shared__ float a2[CLS];
    const int tid = threadIdx.x;
    const int b   = blockIdx.x;

    const float4* src4 = reinterpret_cast<const float4*>(part + (size_t)b * NMC * NJ);
    float4* S4 = reinterpret_cast<float4*>(S);
    for (int idx = tid; idx < (NMC * NJ) / 4; idx += 512) S4[idx] = src4[idx];
    __syncthreads();

    if (tid < NJ) {
        float s = fb1[tid];
        #pragma unroll 8
        for (int mc = 0; mc < NMC; ++mc) s += S[mc * NJ + tid];
        a1s[tid] = fmaxf(s, 0.f);
    }
    __syncthreads();

    if (tid < CLS) {
        float acc = fb2[tid];
        #pragma unroll 4
        for (int j = 0; j < NJ; ++j) acc += a1s[j] * W2[tid * NJ + j];
        a2[tid] = acc;
    }
    __syncthreads();

    if (tid < CLS) {
        float mx = -INFINITY;
        #pragma unroll
        for (int n = 0; n < CLS; ++n) mx = fmaxf(mx, a2[n]);
        float s = 0.f;
        #pragma unroll
        for (int n = 0; n < CLS; ++n) s += expf(a2[n] - mx);
        out[b * CLS + tid] = a2[tid] - mx - logf(s);
    }
}

extern "C" void kernel_launch(void* const* d_in, const int* in_sizes, int n_in,
                              void* d_out, int out_size, void* d_ws, size_t ws_size,
                              hipStream_t stream)
{
    const float* x   = (const float*)d_in[0];
    const float* w1  = (const float*)d_in[1];
    const float* b1  = (const float*)d_in[2];
    const float* t1  = (const float*)d_in[3];
    const float* w2  = (const float*)d_in[4];
    const float* b2  = (const float*)d_in[5];
    const float* t2  = (const float*)d_in[6];
    const float* fw1 = (const float*)d_in[7];
    const float* fb1 = (const float*)d_in[8];
    const float* fw2 = (const float*)d_in[9];
    const float* fb2 = (const float*)d_in[10];

    float* g2   = (float*)d_ws;       // [NG2]
    float* part = g2 + NG2;           // [256*96*100] = 9.8 MB (16B-aligned)

    ka_prep<<<22, 256, 0, stream>>>(x, w1, b1, t1, w2, b2, t2, g2);
    kb_fc1 <<<8 * NMC, 256, 0, stream>>>(g2, fw1, part);
    kc_out <<<256, 512, 0, stream>>>(part, fb1, fw2, fb2, (float*)d_out);
}

// Round 25
// 26.874 us; speedup vs baseline: 1.4449x; 1.4449x over previous
//
#include <hip/hip_runtime.h>
#include <hip/hip_bf16.h>
#include <hip/hip_fp16.h>

#define N1   15996
#define N2   5328
#define NG2  5584
#define NJ   100
#define CLS  10
#define NMC  96      // K chunks: 24 per feature channel
#define MCH  74      // 1776 = 24*74
#define PAIRS 37
#define KROW 52      // LDS row stride in u32 (= 104 f16)
#define LDSF 15340   // f32 units; T(12928) overlays

#define OFF_GA  5824     // u32: gA  [128*52]
#define OFF_G2W 12480    // f32: g2w [348]
#define OFF_Y1  12828    // f32: Y1  [1082]
#define OFF_G   13910    // f32: G   [1076]
#define OFF_Y2  14986    // f32: Y2  [354]

typedef _Float16 h2v  __attribute__((ext_vector_type(2)));
typedef _Float16 f16x8 __attribute__((ext_vector_type(8)));
typedef float    f32x4 __attribute__((ext_vector_type(4)));

static __device__ __forceinline__ unsigned packh2(float a, float b) {
    union { h2v v; unsigned u; } U;
    U.v[0] = (_Float16)a; U.v[1] = (_Float16)b;
    return U.u;
}

// ---- KB: fused prep + fc1 MFMA (R21-verified), part stored as f16 ----
__global__ __launch_bounds__(256)
void kb_fused(const float* __restrict__ x,  const float* __restrict__ w1,
              const float* __restrict__ b1, const float* __restrict__ t1,
              const float* __restrict__ w2, const float* __restrict__ b2,
              const float* __restrict__ t2, const float* __restrict__ W1,
              _Float16* __restrict__ part)
{
    __shared__ float LDS[LDSF];              // 61.4 KB
    unsigned* W1b = (unsigned*)LDS;          // [112][52] u32 = f16[112][104]
    unsigned* gAu = (unsigned*)LDS + OFF_GA; // [128][52]
    float* g2w = LDS + OFF_G2W;
    float* Y1  = LDS + OFF_Y1;
    float* G   = LDS + OFF_G;
    float* Y2  = LDS + OFF_Y2;
    const int tid = threadIdx.x;
    const int bt  = blockIdx.x / NMC;
    const int mc  = blockIdx.x % NMC;
    const int c   = mc / 24;
    const int k0  = (mc % 24) * MCH;
    const int base = bt * 128 + c + 3 * k0;          // <= 5237
    const int jhi  = (base + 347 <= NG2 - 1) ? base + 347 : NG2 - 1;

    // ---- stage W1 chunk as f16 [n][k] ----
    for (int idx = tid; idx < NJ * PAIRS; idx += 256) {
        const int j = idx / PAIRS, p = idx % PAIRS;
        const float2 r = *reinterpret_cast<const float2*>(
            W1 + (size_t)j * 7104 + c * 1776 + k0 + 2 * p);
        W1b[j * KROW + p] = packh2(r.x, r.y);
    }
    for (int idx = tid; idx < NJ * 15; idx += 256) {
        const int j = idx / 15, p = 37 + idx % 15;
        W1b[j * KROW + p] = 0u;
    }
    for (int idx = tid; idx < 12 * KROW; idx += 256)
        W1b[(NJ + idx / KROW) * KROW + (idx % KROW)] = 0u;
    for (int i = tid; i < 348; i += 256) g2w[i] = 0.f;

    // ---- prep segments (R17/R18/R21-verified) ----
    const float it1 = 1.f / (4.f * t1[0]);
    const bool hasB = (jhi >= N2);
    #pragma unroll 1
    for (int seg = 0; seg < 2; ++seg) {
        if (seg == 1 && !hasB) break;
        int ch, plo, phi, doff;
        if (seg == 0) { ch = 0; plo = base; phi = (jhi < N2 - 1) ? jhi : N2 - 1; doff = 0; }
        else          { ch = 1; plo = 0;    phi = jhi - N2;                      doff = N2 - base; }

        const int qa = (plo - 3 > 0) ? plo - 3 : 0;
        const int qb = (phi + 3 < N2 - 1) ? phi + 3 : N2 - 1;
        const int nq = qb - qa + 1;
        const int ga = 3 * qa, gb = 3 * qb + 13;
        const int ng = gb - ga + 1;
        const int ha = (ga - 3 > 0) ? ga - 3 : 0;
        const int hb = (gb + 3 < N1 - 1) ? gb + 3 : N1 - 1;
        const int nh = hb - ha + 1;

        __syncthreads();
        for (int idx = tid; idx < nh; idx += 256) {
            const int n = ha + idx;
            float acc = b1[0];
            #pragma unroll
            for (int k = 0; k < 5; ++k) acc += x[n + k] * w1[k];
            Y1[idx] = fmaxf(acc, 0.f);
        }
        __syncthreads();
        for (int idx = tid; idx < ng; idx += 256) {
            const int n = ga + idx;
            float m = -INFINITY;
            #pragma unroll
            for (int d = 0; d < 7; ++d) {
                int p = n + d - 3;
                if ((unsigned)p < (unsigned)N1) {
                    float z = (float)(d - 3);
                    m = fmaxf(m, Y1[p - ha] - z * z * it1);
                }
            }
            G[idx] = m;
        }
        __syncthreads();
        for (int idx = tid; idx < nq; idx += 256) {
            const int q = qa + idx;
            float acc = b2[ch];
            #pragma unroll
            for (int k = 0; k < 5; ++k) {
                #pragma unroll
                for (int i = 0; i < 2; ++i)
                    acc += G[i + 3 * (q + k) - ga] * w2[(ch * 2 + i) * 5 + k];
            }
            Y2[idx] = fmaxf(acc, 0.f);
        }
        __syncthreads();
        {
            const float it2 = 1.f / (4.f * t2[ch]);
            for (int idx = tid; idx <= phi - plo; idx += 256) {
                const int p = plo + idx;
                float m = -INFINITY;
                #pragma unroll
                for (int d = 0; d < 7; ++d) {
                    int q = p + d - 3;
                    if ((unsigned)q < (unsigned)N2) {
                        float z = (float)(d - 3);
                        m = fmaxf(m, Y2[q - qa] - z * z * it2);
                    }
                }
                g2w[doff + idx] = m;
            }
        }
    }
    __syncthreads();

    // ---- build A operand ----
    for (int idx = tid; idx < 128 * PAIRS; idx += 256) {
        const int b = idx / PAIRS, p = idx % PAIRS;
        gAu[b * KROW + p] = packh2(g2w[b + 6 * p], g2w[b + 6 * p + 3]);
    }
    for (int idx = tid; idx < 128 * 15; idx += 256) {
        const int b = idx / 15, p = 37 + idx % 15;
        gAu[b * KROW + p] = 0u;
    }
    __syncthreads();

    // ---- MFMA ----
    const int w  = tid >> 6, l = tid & 63;
    const int lr = l & 15, lg = l >> 4;
    f32x4 acc[2][7];
    #pragma unroll
    for (int mt = 0; mt < 2; ++mt)
        #pragma unroll
        for (int nt = 0; nt < 7; ++nt)
            acc[mt][nt] = (f32x4){0.f, 0.f, 0.f, 0.f};

    union FU { uint4 u; f16x8 h; };
    #pragma unroll
    for (int ks = 0; ks < 3; ++ks) {
        const int kb = ks * 16 + lg * 4;
        FU a0, a1, bfr[7];
        a0.u = *reinterpret_cast<const uint4*>(gAu + (32 * w + lr) * KROW + kb);
        a1.u = *reinterpret_cast<const uint4*>(gAu + (32 * w + 16 + lr) * KROW + kb);
        #pragma unroll
        for (int nt = 0; nt < 7; ++nt)
            bfr[nt].u = *reinterpret_cast<const uint4*>(W1b + (nt * 16 + lr) * KROW + kb);
        #pragma unroll
        for (int nt = 0; nt < 7; ++nt) {
            acc[0][nt] = __builtin_amdgcn_mfma_f32_16x16x32_f16(a0.h, bfr[nt].h, acc[0][nt], 0, 0, 0);
            acc[1][nt] = __builtin_amdgcn_mfma_f32_16x16x32_f16(a1.h, bfr[nt].h, acc[1][nt], 0, 0, 0);
        }
    }
    __syncthreads();

    float* T = LDS;    // [128][101] padded
    #pragma unroll
    for (int mt = 0; mt < 2; ++mt)
        #pragma unroll
        for (int nt = 0; nt < 7; ++nt)
            #pragma unroll
            for (int r = 0; r < 4; ++r) {
                const int brow = 32 * w + mt * 16 + lg * 4 + r;
                const int j    = nt * 16 + lr;
                if (j < NJ) T[brow * 101 + j] = acc[mt][nt][r];
            }
    __syncthreads();

    // part[(b*NMC + mc)*100 + j] as f16 (halved traffic)
    for (int idx = tid; idx < 128 * NJ; idx += 256) {
        const int bl = idx / NJ, j = idx - bl * NJ;
        part[((size_t)(bt * 128 + bl) * NMC + mc) * NJ + j] = (_Float16)T[bl * 101 + j];
    }
}

// ---- KC: reduce (f16 part) + fc2 + log_softmax; 512 threads ----
__global__ __launch_bounds__(512)
void kc_out(const _Float16* __restrict__ part, const float* __restrict__ fb1,
            const float* __restrict__ W2,  const float* __restrict__ fb2,
            float* __restrict__ out)
{
    __shared__ _Float16 S[NMC * NJ];   // 19.2 KB
    __shared__ float a1s[NJ];
    __shared__ float a2[CLS];
    const int tid = threadIdx.x;
    const int b   = blockIdx.x;

    // stage 9600 f16 = 1200 uint4 loads (base b*19200 B, 16B-aligned)
    const uint4* src4 = reinterpret_cast<const uint4*>(part + (size_t)b * NMC * NJ);
    uint4* S4 = reinterpret_cast<uint4*>(S);
    for (int idx = tid; idx < (NMC * NJ) / 8; idx += 512) S4[idx] = src4[idx];
    __syncthreads();

    if (tid < NJ) {
        float s = fb1[tid];
        #pragma unroll 8
        for (int mc = 0; mc < NMC; ++mc) s += (float)S[mc * NJ + tid];
        a1s[tid] = fmaxf(s, 0.f);
    }
    __syncthreads();

    if (tid < CLS) {
        float acc = fb2[tid];
        #pragma unroll 4
        for (int j = 0; j < NJ; ++j) acc += a1s[j] * W2[tid * NJ + j];
        a2[tid] = acc;
    }
    __syncthreads();

    if (tid < CLS) {
        float mx = -INFINITY;
        #pragma unroll
        for (int n = 0; n < CLS; ++n) mx = fmaxf(mx, a2[n]);
        float s = 0.f;
        #pragma unroll
        for (int n = 0; n < CLS; ++n) s += expf(a2[n] - mx);
        out[b * CLS + tid] = a2[tid] - mx - logf(s);
    }
}

extern "C" void kernel_launch(void* const* d_in, const int* in_sizes, int n_in,
                              void* d_out, int out_size, void* d_ws, size_t ws_size,
                              hipStream_t stream)
{
    const float* x   = (const float*)d_in[0];
    const float* w1  = (const float*)d_in[1];
    const float* b1  = (const float*)d_in[2];
    const float* t1  = (const float*)d_in[3];
    const float* w2  = (const float*)d_in[4];
    const float* b2  = (const float*)d_in[5];
    const float* t2  = (const float*)d_in[6];
    const float* fw1 = (const float*)d_in[7];
    const float* fb1 = (const float*)d_in[8];
    const float* fw2 = (const float*)d_in[9];
    const float* fb2 = (const float*)d_in[10];

    _Float16* part = (_Float16*)d_ws;   // [256*96*100] f16 = 4.9 MB

    kb_fused<<<2 * NMC, 256, 0, stream>>>(x, w1, b1, t1, w2, b2, t2, fw1, part);
    kc_out  <<<256, 512, 0, stream>>>(part, fb1, fw2, fb2, (float*)d_out);
}

// Round 26
// 25.601 us; speedup vs baseline: 1.5167x; 1.0497x over previous
//
#include <hip/hip_runtime.h>
#include <hip/hip_bf16.h>
#include <hip/hip_fp16.h>

#define N1   15996
#define N2   5328
#define NG2  5584
#define NJ   100
#define CLS  10
#define NMC  96      // K chunks: 24 per feature channel
#define MCH  74      // 1776 = 24*74
#define PAIRS 37
#define KROW 52      // LDS row stride in u32 (= 104 f16)
#define LDSF 15340   // f32 units; f16-T (13312 f16 = 6656 words) overlays

#define OFF_GA  5824     // u32: gA  [128*52]
#define OFF_G2W 12480    // f32: g2w [348]
#define OFF_Y1  12828    // f32: Y1  [1082]
#define OFF_G   13910    // f32: G   [1076]
#define OFF_Y2  14986    // f32: Y2  [354]

#define TROW 104         // T row stride in f16 (208 B; 2-way bank alias max)

typedef _Float16 h2v  __attribute__((ext_vector_type(2)));
typedef _Float16 f16x8 __attribute__((ext_vector_type(8)));
typedef float    f32x4 __attribute__((ext_vector_type(4)));

static __device__ __forceinline__ unsigned packh2(float a, float b) {
    union { h2v v; unsigned u; } U;
    U.v[0] = (_Float16)a; U.v[1] = (_Float16)b;
    return U.u;
}

// ---- KB: fused prep + fc1 MFMA (R21/R25-verified), f16 T + uint2 part write ----
__global__ __launch_bounds__(256)
void kb_fused(const float* __restrict__ x,  const float* __restrict__ w1,
              const float* __restrict__ b1, const float* __restrict__ t1,
              const float* __restrict__ w2, const float* __restrict__ b2,
              const float* __restrict__ t2, const float* __restrict__ W1,
              _Float16* __restrict__ part)
{
    __shared__ float LDS[LDSF];              // 61.4 KB
    unsigned* W1b = (unsigned*)LDS;          // [112][52] u32 = f16[112][104]
    unsigned* gAu = (unsigned*)LDS + OFF_GA; // [128][52]
    float* g2w = LDS + OFF_G2W;
    float* Y1  = LDS + OFF_Y1;
    float* G   = LDS + OFF_G;
    float* Y2  = LDS + OFF_Y2;
    const int tid = threadIdx.x;
    const int bt  = blockIdx.x / NMC;
    const int mc  = blockIdx.x % NMC;
    const int c   = mc / 24;
    const int k0  = (mc % 24) * MCH;
    const int base = bt * 128 + c + 3 * k0;          // <= 5237
    const int jhi  = (base + 347 <= NG2 - 1) ? base + 347 : NG2 - 1;

    // ---- stage W1 chunk as f16 [n][k] ----
    for (int idx = tid; idx < NJ * PAIRS; idx += 256) {
        const int j = idx / PAIRS, p = idx % PAIRS;
        const float2 r = *reinterpret_cast<const float2*>(
            W1 + (size_t)j * 7104 + c * 1776 + k0 + 2 * p);
        W1b[j * KROW + p] = packh2(r.x, r.y);
    }
    for (int idx = tid; idx < NJ * 15; idx += 256) {
        const int j = idx / 15, p = 37 + idx % 15;
        W1b[j * KROW + p] = 0u;
    }
    for (int idx = tid; idx < 12 * KROW; idx += 256)
        W1b[(NJ + idx / KROW) * KROW + (idx % KROW)] = 0u;
    for (int i = tid; i < 348; i += 256) g2w[i] = 0.f;

    // ---- prep segments (R17/R18/R21-verified) ----
    const float it1 = 1.f / (4.f * t1[0]);
    const bool hasB = (jhi >= N2);
    #pragma unroll 1
    for (int seg = 0; seg < 2; ++seg) {
        if (seg == 1 && !hasB) break;
        int ch, plo, phi, doff;
        if (seg == 0) { ch = 0; plo = base; phi = (jhi < N2 - 1) ? jhi : N2 - 1; doff = 0; }
        else          { ch = 1; plo = 0;    phi = jhi - N2;                      doff = N2 - base; }

        const int qa = (plo - 3 > 0) ? plo - 3 : 0;
        const int qb = (phi + 3 < N2 - 1) ? phi + 3 : N2 - 1;
        const int nq = qb - qa + 1;
        const int ga = 3 * qa, gb = 3 * qb + 13;
        const int ng = gb - ga + 1;
        const int ha = (ga - 3 > 0) ? ga - 3 : 0;
        const int hb = (gb + 3 < N1 - 1) ? gb + 3 : N1 - 1;
        const int nh = hb - ha + 1;

        __syncthreads();
        for (int idx = tid; idx < nh; idx += 256) {
            const int n = ha + idx;
            float acc = b1[0];
            #pragma unroll
            for (int k = 0; k < 5; ++k) acc += x[n + k] * w1[k];
            Y1[idx] = fmaxf(acc, 0.f);
        }
        __syncthreads();
        for (int idx = tid; idx < ng; idx += 256) {
            const int n = ga + idx;
            float m = -INFINITY;
            #pragma unroll
            for (int d = 0; d < 7; ++d) {
                int p = n + d - 3;
                if ((unsigned)p < (unsigned)N1) {
                    float z = (float)(d - 3);
                    m = fmaxf(m, Y1[p - ha] - z * z * it1);
                }
            }
            G[idx] = m;
        }
        __syncthreads();
        for (int idx = tid; idx < nq; idx += 256) {
            const int q = qa + idx;
            float acc = b2[ch];
            #pragma unroll
            for (int k = 0; k < 5; ++k) {
                #pragma unroll
                for (int i = 0; i < 2; ++i)
                    acc += G[i + 3 * (q + k) - ga] * w2[(ch * 2 + i) * 5 + k];
            }
            Y2[idx] = fmaxf(acc, 0.f);
        }
        __syncthreads();
        {
            const float it2 = 1.f / (4.f * t2[ch]);
            for (int idx = tid; idx <= phi - plo; idx += 256) {
                const int p = plo + idx;
                float m = -INFINITY;
                #pragma unroll
                for (int d = 0; d < 7; ++d) {
                    int q = p + d - 3;
                    if ((unsigned)q < (unsigned)N2) {
                        float z = (float)(d - 3);
                        m = fmaxf(m, Y2[q - qa] - z * z * it2);
                    }
                }
                g2w[doff + idx] = m;
            }
        }
    }
    __syncthreads();

    // ---- build A operand ----
    for (int idx = tid; idx < 128 * PAIRS; idx += 256) {
        const int b = idx / PAIRS, p = idx % PAIRS;
        gAu[b * KROW + p] = packh2(g2w[b + 6 * p], g2w[b + 6 * p + 3]);
    }
    for (int idx = tid; idx < 128 * 15; idx += 256) {
        const int b = idx / 15, p = 37 + idx % 15;
        gAu[b * KROW + p] = 0u;
    }
    __syncthreads();

    // ---- MFMA ----
    const int w  = tid >> 6, l = tid & 63;
    const int lr = l & 15, lg = l >> 4;
    f32x4 acc[2][7];
    #pragma unroll
    for (int mt = 0; mt < 2; ++mt)
        #pragma unroll
        for (int nt = 0; nt < 7; ++nt)
            acc[mt][nt] = (f32x4){0.f, 0.f, 0.f, 0.f};

    union FU { uint4 u; f16x8 h; };
    #pragma unroll
    for (int ks = 0; ks < 3; ++ks) {
        const int kb = ks * 16 + lg * 4;
        FU a0, a1, bfr[7];
        a0.u = *reinterpret_cast<const uint4*>(gAu + (32 * w + lr) * KROW + kb);
        a1.u = *reinterpret_cast<const uint4*>(gAu + (32 * w + 16 + lr) * KROW + kb);
        #pragma unroll
        for (int nt = 0; nt < 7; ++nt)
            bfr[nt].u = *reinterpret_cast<const uint4*>(W1b + (nt * 16 + lr) * KROW + kb);
        #pragma unroll
        for (int nt = 0; nt < 7; ++nt) {
            acc[0][nt] = __builtin_amdgcn_mfma_f32_16x16x32_f16(a0.h, bfr[nt].h, acc[0][nt], 0, 0, 0);
            acc[1][nt] = __builtin_amdgcn_mfma_f32_16x16x32_f16(a1.h, bfr[nt].h, acc[1][nt], 0, 0, 0);
        }
    }
    __syncthreads();   // staging dead; reuse LDS as f16 T

    _Float16* Th = (_Float16*)LDS;   // [128][TROW] f16 (26.6 KB)
    #pragma unroll
    for (int mt = 0; mt < 2; ++mt)
        #pragma unroll
        for (int nt = 0; nt < 7; ++nt)
            #pragma unroll
            for (int r = 0; r < 4; ++r) {
                const int brow = 32 * w + mt * 16 + lg * 4 + r;
                const int j    = nt * 16 + lr;
                if (j < NJ) Th[brow * TROW + j] = (_Float16)acc[mt][nt][r];
            }
    __syncthreads();

    // part write: uint2 (4 f16) per op — 3200 per block, coalesced 8B runs
    const uint2* Tu = reinterpret_cast<const uint2*>(Th);    // row stride 26 uint2
    uint2* pu = reinterpret_cast<uint2*>(part);
    for (int idx = tid; idx < 128 * 25; idx += 256) {
        const int bl = idx / 25, jq = idx % 25;
        pu[((size_t)(bt * 128 + bl) * NMC + mc) * 25 + jq] = Tu[bl * 26 + jq];
    }
}

// ---- KC: reduce (f16 part) + fc2 + log_softmax; 512 threads (R25) ----
__global__ __launch_bounds__(512)
void kc_out(const _Float16* __restrict__ part, const float* __restrict__ fb1,
            const float* __restrict__ W2,  const float* __restrict__ fb2,
            float* __restrict__ out)
{
    __shared__ _Float16 S[NMC * NJ];   // 19.2 KB
    __shared__ float a1s[NJ];
    __shared__ float a2[CLS];
    const int tid = threadIdx.x;
    const int b   = blockIdx.x;

    const uint4* src4 = reinterpret_cast<const uint4*>(part + (size_t)b * NMC * NJ);
    uint4* S4 = reinterpret_cast<uint4*>(S);
    for (int idx = tid; idx < (NMC * NJ) / 8; idx += 512) S4[idx] = src4[idx];
    __syncthreads();

    if (tid < NJ) {
        float s = fb1[tid];
        #pragma unroll 8
        for (int mc = 0; mc < NMC; ++mc) s += (float)S[mc * NJ + tid];
        a1s[tid] = fmaxf(s, 0.f);
    }
    __syncthreads();

    if (tid < CLS) {
        float acc = fb2[tid];
        #pragma unroll 4
        for (int j = 0; j < NJ; ++j) acc += a1s[j] * W2[tid * NJ + j];
        a2[tid] = acc;
    }
    __syncthreads();

    if (tid < CLS) {
        float mx = -INFINITY;
        #pragma unroll
        for (int n = 0; n < CLS; ++n) mx = fmaxf(mx, a2[n]);
        float s = 0.f;
        #pragma unroll
        for (int n = 0; n < CLS; ++n) s += expf(a2[n] - mx);
        out[b * CLS + tid] = a2[tid] - mx - logf(s);
    }
}

extern "C" void kernel_launch(void* const* d_in, const int* in_sizes, int n_in,
                              void* d_out, int out_size, void* d_ws, size_t ws_size,
                              hipStream_t stream)
{
    const float* x   = (const float*)d_in[0];
    const float* w1  = (const float*)d_in[1];
    const float* b1  = (const float*)d_in[2];
    const float* t1  = (const float*)d_in[3];
    const float* w2  = (const float*)d_in[4];
    const float* b2  = (const float*)d_in[5];
    const float* t2  = (const float*)d_in[6];
    const float* fw1 = (const float*)d_in[7];
    const float* fb1 = (const float*)d_in[8];
    const float* fw2 = (const float*)d_in[9];
    const float* fb2 = (const float*)d_in[10];

    _Float16* part = (_Float16*)d_ws;   // [256*96*100] f16 = 4.9 MB

    kb_fused<<<2 * NMC, 256, 0, stream>>>(x, w1, b1, t1, w2, b2, t2, fw1, part);
    kc_out  <<<256, 512, 0, stream>>>(part, fb1, fw2, fb2, (float*)d_out);
}

// Round 27
// 21.710 us; speedup vs baseline: 1.7886x; 1.1792x over previous
//
#include <hip/hip_runtime.h>
#include <hip/hip_bf16.h>
#include <hip/hip_fp16.h>

#define N1   15996
#define N2   5328
#define NG2  5584
#define NJ   100
#define CLS  10
#define NMC  96      // K chunks: 24 per feature channel
#define MCH  74      // 1776 = 24*74
#define PAIRS 37
#define KROW 52      // LDS row stride in u32 (= 104 f16)
#define LDSF 15340   // f32 units; f16-T overlays

#define OFF_GA  5824     // u32: gA  [128*52]
#define OFF_G2W 12480    // f32: g2w [348]
#define OFF_Y1  12828    // f32: Y1  [1082]
#define OFF_G   13910    // f32: G   [1076]
#define OFF_Y2  14986    // f32: Y2  [354]

#define TROW 104         // T row stride in f16 (208 B)
#define NT   512         // threads per block (8 waves)

typedef _Float16 h2v  __attribute__((ext_vector_type(2)));
typedef _Float16 f16x8 __attribute__((ext_vector_type(8)));
typedef float    f32x4 __attribute__((ext_vector_type(4)));

static __device__ __forceinline__ unsigned packh2(float a, float b) {
    union { h2v v; unsigned u; } U;
    U.v[0] = (_Float16)a; U.v[1] = (_Float16)b;
    return U.u;
}

// ---- KB: fused prep + fc1 MFMA, 512 threads (8 waves; wave w -> M rows [16w,16w+16)) ----
__global__ __launch_bounds__(NT)
void kb_fused(const float* __restrict__ x,  const float* __restrict__ w1,
              const float* __restrict__ b1, const float* __restrict__ t1,
              const float* __restrict__ w2, const float* __restrict__ b2,
              const float* __restrict__ t2, const float* __restrict__ W1,
              _Float16* __restrict__ part)
{
    __shared__ float LDS[LDSF];              // 61.4 KB
    unsigned* W1b = (unsigned*)LDS;          // [112][52] u32 = f16[112][104]
    unsigned* gAu = (unsigned*)LDS + OFF_GA; // [128][52]
    float* g2w = LDS + OFF_G2W;
    float* Y1  = LDS + OFF_Y1;
    float* G   = LDS + OFF_G;
    float* Y2  = LDS + OFF_Y2;
    const int tid = threadIdx.x;
    const int bt  = blockIdx.x / NMC;
    const int mc  = blockIdx.x % NMC;
    const int c   = mc / 24;
    const int k0  = (mc % 24) * MCH;
    const int base = bt * 128 + c + 3 * k0;          // <= 5237
    const int jhi  = (base + 347 <= NG2 - 1) ? base + 347 : NG2 - 1;

    // ---- stage W1 chunk as f16 [n][k] ----
    for (int idx = tid; idx < NJ * PAIRS; idx += NT) {
        const int j = idx / PAIRS, p = idx % PAIRS;
        const float2 r = *reinterpret_cast<const float2*>(
            W1 + (size_t)j * 7104 + c * 1776 + k0 + 2 * p);
        W1b[j * KROW + p] = packh2(r.x, r.y);
    }
    for (int idx = tid; idx < NJ * 15; idx += NT) {
        const int j = idx / 15, p = 37 + idx % 15;
        W1b[j * KROW + p] = 0u;
    }
    for (int idx = tid; idx < 12 * KROW; idx += NT)
        W1b[(NJ + idx / KROW) * KROW + (idx % KROW)] = 0u;
    for (int i = tid; i < 348; i += NT) g2w[i] = 0.f;

    // ---- prep segments (R17/R18/R21-verified logic; NT-stride) ----
    const float it1 = 1.f / (4.f * t1[0]);
    const bool hasB = (jhi >= N2);
    #pragma unroll 1
    for (int seg = 0; seg < 2; ++seg) {
        if (seg == 1 && !hasB) break;
        int ch, plo, phi, doff;
        if (seg == 0) { ch = 0; plo = base; phi = (jhi < N2 - 1) ? jhi : N2 - 1; doff = 0; }
        else          { ch = 1; plo = 0;    phi = jhi - N2;                      doff = N2 - base; }

        const int qa = (plo - 3 > 0) ? plo - 3 : 0;
        const int qb = (phi + 3 < N2 - 1) ? phi + 3 : N2 - 1;
        const int nq = qb - qa + 1;
        const int ga = 3 * qa, gb = 3 * qb + 13;
        const int ng = gb - ga + 1;
        const int ha = (ga - 3 > 0) ? ga - 3 : 0;
        const int hb = (gb + 3 < N1 - 1) ? gb + 3 : N1 - 1;
        const int nh = hb - ha + 1;

        __syncthreads();
        for (int idx = tid; idx < nh; idx += NT) {
            const int n = ha + idx;
            float acc = b1[0];
            #pragma unroll
            for (int k = 0; k < 5; ++k) acc += x[n + k] * w1[k];
            Y1[idx] = fmaxf(acc, 0.f);
        }
        __syncthreads();
        for (int idx = tid; idx < ng; idx += NT) {
            const int n = ga + idx;
            float m = -INFINITY;
            #pragma unroll
            for (int d = 0; d < 7; ++d) {
                int p = n + d - 3;
                if ((unsigned)p < (unsigned)N1) {
                    float z = (float)(d - 3);
                    m = fmaxf(m, Y1[p - ha] - z * z * it1);
                }
            }
            G[idx] = m;
        }
        __syncthreads();
        for (int idx = tid; idx < nq; idx += NT) {
            const int q = qa + idx;
            float acc = b2[ch];
            #pragma unroll
            for (int k = 0; k < 5; ++k) {
                #pragma unroll
                for (int i = 0; i < 2; ++i)
                    acc += G[i + 3 * (q + k) - ga] * w2[(ch * 2 + i) * 5 + k];
            }
            Y2[idx] = fmaxf(acc, 0.f);
        }
        __syncthreads();
        {
            const float it2 = 1.f / (4.f * t2[ch]);
            for (int idx = tid; idx <= phi - plo; idx += NT) {
                const int p = plo + idx;
                float m = -INFINITY;
                #pragma unroll
                for (int d = 0; d < 7; ++d) {
                    int q = p + d - 3;
                    if ((unsigned)q < (unsigned)N2) {
                        float z = (float)(d - 3);
                        m = fmaxf(m, Y2[q - qa] - z * z * it2);
                    }
                }
                g2w[doff + idx] = m;
            }
        }
    }
    __syncthreads();

    // ---- build A operand ----
    for (int idx = tid; idx < 128 * PAIRS; idx += NT) {
        const int b = idx / PAIRS, p = idx % PAIRS;
        gAu[b * KROW + p] = packh2(g2w[b + 6 * p], g2w[b + 6 * p + 3]);
    }
    for (int idx = tid; idx < 128 * 15; idx += NT) {
        const int b = idx / 15, p = 37 + idx % 15;
        gAu[b * KROW + p] = 0u;
    }
    __syncthreads();

    // ---- MFMA: 8 waves; wave w -> M rows [16w, 16w+16), 7 N tiles, K = 3 steps ----
    const int w  = tid >> 6, l = tid & 63;
    const int lr = l & 15, lg = l >> 4;
    f32x4 acc[7];
    #pragma unroll
    for (int nt = 0; nt < 7; ++nt) acc[nt] = (f32x4){0.f, 0.f, 0.f, 0.f};

    union FU { uint4 u; f16x8 h; };
    #pragma unroll
    for (int ks = 0; ks < 3; ++ks) {
        const int kb = ks * 16 + lg * 4;
        FU a, bfr[7];
        a.u = *reinterpret_cast<const uint4*>(gAu + (16 * w + lr) * KROW + kb);
        #pragma unroll
        for (int nt = 0; nt < 7; ++nt)
            bfr[nt].u = *reinterpret_cast<const uint4*>(W1b + (nt * 16 + lr) * KROW + kb);
        #pragma unroll
        for (int nt = 0; nt < 7; ++nt)
            acc[nt] = __builtin_amdgcn_mfma_f32_16x16x32_f16(a.h, bfr[nt].h, acc[nt], 0, 0, 0);
    }
    __syncthreads();   // staging dead; reuse LDS as f16 T

    _Float16* Th = (_Float16*)LDS;   // [128][TROW] f16 (26.6 KB)
    #pragma unroll
    for (int nt = 0; nt < 7; ++nt)
        #pragma unroll
        for (int r = 0; r < 4; ++r) {
            const int brow = 16 * w + lg * 4 + r;
            const int j    = nt * 16 + lr;
            if (j < NJ) Th[brow * TROW + j] = (_Float16)acc[nt][r];
        }
    __syncthreads();

    // part write: uint2 (4 f16) per op — 3200 per block, coalesced 8B runs
    const uint2* Tu = reinterpret_cast<const uint2*>(Th);    // row stride 26 uint2
    uint2* pu = reinterpret_cast<uint2*>(part);
    for (int idx = tid; idx < 128 * 25; idx += NT) {
        const int bl = idx / 25, jq = idx % 25;
        pu[((size_t)(bt * 128 + bl) * NMC + mc) * 25 + jq] = Tu[bl * 26 + jq];
    }
}

// ---- KC: reduce (f16 part) + fc2 + log_softmax; 512 threads (R25/R26) ----
__global__ __launch_bounds__(512)
void kc_out(const _Float16* __restrict__ part, const float* __restrict__ fb1,
            const float* __restrict__ W2,  const float* __restrict__ fb2,
            float* __restrict__ out)
{
    __shared__ _Float16 S[NMC * NJ];   // 19.2 KB
    __shared__ float a1s[NJ];
    __shared__ float a2[CLS];
    const int tid = threadIdx.x;
    const int b   = blockIdx.x;

    const uint4* src4 = reinterpret_cast<const uint4*>(part + (size_t)b * NMC * NJ);
    uint4* S4 = reinterpret_cast<uint4*>(S);
    for (int idx = tid; idx < (NMC * NJ) / 8; idx += 512) S4[idx] = src4[idx];
    __syncthreads();

    if (tid < NJ) {
        float s = fb1[tid];
        #pragma unroll 8
        for (int mc = 0; mc < NMC; ++mc) s += (float)S[mc * NJ + tid];
        a1s[tid] = fmaxf(s, 0.f);
    }
    __syncthreads();

    if (tid < CLS) {
        float acc = fb2[tid];
        #pragma unroll 4
        for (int j = 0; j < NJ; ++j) acc += a1s[j] * W2[tid * NJ + j];
        a2[tid] = acc;
    }
    __syncthreads();

    if (tid < CLS) {
        float mx = -INFINITY;
        #pragma unroll
        for (int n = 0; n < CLS; ++n) mx = fmaxf(mx, a2[n]);
        float s = 0.f;
        #pragma unroll
        for (int n = 0; n < CLS; ++n) s += expf(a2[n] - mx);
        out[b * CLS + tid] = a2[tid] - mx - logf(s);
    }
}

extern "C" void kernel_launch(void* const* d_in, const int* in_sizes, int n_in,
                              void* d_out, int out_size, void* d_ws, size_t ws_size,
                              hipStream_t stream)
{
    const float* x   = (const float*)d_in[0];
    const float* w1  = (const float*)d_in[1];
    const float* b1  = (const float*)d_in[2];
    const float* t1  = (const float*)d_in[3];
    const float* w2  = (const float*)d_in[4];
    const float* b2  = (const float*)d_in[5];
    const float* t2  = (const float*)d_in[6];
    const float* fw1 = (const float*)d_in[7];
    const float* fb1 = (const float*)d_in[8];
    const float* fw2 = (const float*)d_in[9];
    const float* fb2 = (const float*)d_in[10];

    _Float16* part = (_Float16*)d_ws;   // [256*96*100] f16 = 4.9 MB

    kb_fused<<<2 * NMC, NT, 0, stream>>>(x, w1, b1, t1, w2, b2, t2, fw1, part);
    kc_out  <<<256, 512, 0, stream>>>(part, fb1, fw2, fb2, (float*)d_out);
}

// Round 28
// 21.623 us; speedup vs baseline: 1.7958x; 1.0040x over previous
//
#include <hip/hip_runtime.h>
#include <hip/hip_bf16.h>
#include <hip/hip_fp16.h>

#define N1   15996
#define N2   5328
#define NG2  5584
#define NJ   100
#define CLS  10
#define NMC  96      // K chunks: 24 per feature channel
#define MCH  74      // 1776 = 24*74
#define PAIRS 37
#define KROW 52      // LDS row stride in u32 (= 104 f16)
#define LDSF 15340   // f32 units; f16-T overlays

#define OFF_GA  5824     // u32: gA  [128*52]
#define OFF_G2W 12480    // f32: g2w [348]
#define OFF_Y1  12828    // f32: Y1  [1082]
#define OFF_G   13910    // f32: G   [1076]
#define OFF_Y2  14986    // f32: Y2  [354]

#define TROW 104         // T row stride in f16 (208 B)
#define NT   512         // threads per block (8 waves)

typedef _Float16 h2v  __attribute__((ext_vector_type(2)));
typedef _Float16 f16x8 __attribute__((ext_vector_type(8)));
typedef float    f32x4 __attribute__((ext_vector_type(4)));

static __device__ __forceinline__ unsigned packh2(float a, float b) {
    union { h2v v; unsigned u; } U;
    U.v[0] = (_Float16)a; U.v[1] = (_Float16)b;
    return U.u;
}

// ---- KB: fused prep + fc1 MFMA, 512 threads (8 waves; wave w -> M rows [16w,16w+16)) ----
__global__ __launch_bounds__(NT)
void kb_fused(const float* __restrict__ x,  const float* __restrict__ w1,
              const float* __restrict__ b1, const float* __restrict__ t1,
              const float* __restrict__ w2, const float* __restrict__ b2,
              const float* __restrict__ t2, const float* __restrict__ W1,
              _Float16* __restrict__ part)
{
    __shared__ float LDS[LDSF];              // 61.4 KB
    unsigned* W1b = (unsigned*)LDS;          // [112][52] u32 = f16[112][104]
    unsigned* gAu = (unsigned*)LDS + OFF_GA; // [128][52]
    float* g2w = LDS + OFF_G2W;
    float* Y1  = LDS + OFF_Y1;
    float* G   = LDS + OFF_G;
    float* Y2  = LDS + OFF_Y2;
    const int tid = threadIdx.x;
    const int bt  = blockIdx.x / NMC;
    const int mc  = blockIdx.x % NMC;
    const int c   = mc / 24;
    const int k0  = (mc % 24) * MCH;
    const int base = bt * 128 + c + 3 * k0;          // <= 5237
    const int jhi  = (base + 347 <= NG2 - 1) ? base + 347 : NG2 - 1;

    // ---- stage W1 chunk as f16 [n][k] ----
    for (int idx = tid; idx < NJ * PAIRS; idx += NT) {
        const int j = idx / PAIRS, p = idx % PAIRS;
        const float2 r = *reinterpret_cast<const float2*>(
            W1 + (size_t)j * 7104 + c * 1776 + k0 + 2 * p);
        W1b[j * KROW + p] = packh2(r.x, r.y);
    }
    for (int idx = tid; idx < NJ * 15; idx += NT) {
        const int j = idx / 15, p = 37 + idx % 15;
        W1b[j * KROW + p] = 0u;
    }
    for (int idx = tid; idx < 12 * KROW; idx += NT)
        W1b[(NJ + idx / KROW) * KROW + (idx % KROW)] = 0u;
    for (int i = tid; i < 348; i += NT) g2w[i] = 0.f;

    // ---- prep segments (R17/R18/R21-verified logic; NT-stride) ----
    const float it1 = 1.f / (4.f * t1[0]);
    const bool hasB = (jhi >= N2);
    #pragma unroll 1
    for (int seg = 0; seg < 2; ++seg) {
        if (seg == 1 && !hasB) break;
        int ch, plo, phi, doff;
        if (seg == 0) { ch = 0; plo = base; phi = (jhi < N2 - 1) ? jhi : N2 - 1; doff = 0; }
        else          { ch = 1; plo = 0;    phi = jhi - N2;                      doff = N2 - base; }

        const int qa = (plo - 3 > 0) ? plo - 3 : 0;
        const int qb = (phi + 3 < N2 - 1) ? phi + 3 : N2 - 1;
        const int nq = qb - qa + 1;
        const int ga = 3 * qa, gb = 3 * qb + 13;
        const int ng = gb - ga + 1;
        const int ha = (ga - 3 > 0) ? ga - 3 : 0;
        const int hb = (gb + 3 < N1 - 1) ? gb + 3 : N1 - 1;
        const int nh = hb - ha + 1;

        __syncthreads();
        for (int idx = tid; idx < nh; idx += NT) {
            const int n = ha + idx;
            float acc = b1[0];
            #pragma unroll
            for (int k = 0; k < 5; ++k) acc += x[n + k] * w1[k];
            Y1[idx] = fmaxf(acc, 0.f);
        }
        __syncthreads();
        for (int idx = tid; idx < ng; idx += NT) {
            const int n = ga + idx;
            float m = -INFINITY;
            #pragma unroll
            for (int d = 0; d < 7; ++d) {
                int p = n + d - 3;
                if ((unsigned)p < (unsigned)N1) {
                    float z = (float)(d - 3);
                    m = fmaxf(m, Y1[p - ha] - z * z * it1);
                }
            }
            G[idx] = m;
        }
        __syncthreads();
        for (int idx = tid; idx < nq; idx += NT) {
            const int q = qa + idx;
            float acc = b2[ch];
            #pragma unroll
            for (int k = 0; k < 5; ++k) {
                #pragma unroll
                for (int i = 0; i < 2; ++i)
                    acc += G[i + 3 * (q + k) - ga] * w2[(ch * 2 + i) * 5 + k];
            }
            Y2[idx] = fmaxf(acc, 0.f);
        }
        __syncthreads();
        {
            const float it2 = 1.f / (4.f * t2[ch]);
            for (int idx = tid; idx <= phi - plo; idx += NT) {
                const int p = plo + idx;
                float m = -INFINITY;
                #pragma unroll
                for (int d = 0; d < 7; ++d) {
                    int q = p + d - 3;
                    if ((unsigned)q < (unsigned)N2) {
                        float z = (float)(d - 3);
                        m = fmaxf(m, Y2[q - qa] - z * z * it2);
                    }
                }
                g2w[doff + idx] = m;
            }
        }
    }
    __syncthreads();

    // ---- build A operand ----
    for (int idx = tid; idx < 128 * PAIRS; idx += NT) {
        const int b = idx / PAIRS, p = idx % PAIRS;
        gAu[b * KROW + p] = packh2(g2w[b + 6 * p], g2w[b + 6 * p + 3]);
    }
    for (int idx = tid; idx < 128 * 15; idx += NT) {
        const int b = idx / 15, p = 37 + idx % 15;
        gAu[b * KROW + p] = 0u;
    }
    __syncthreads();

    // ---- MFMA: 8 waves; wave w -> M rows [16w, 16w+16), 7 N tiles, K = 3 steps ----
    const int w  = tid >> 6, l = tid & 63;
    const int lr = l & 15, lg = l >> 4;
    f32x4 acc[7];
    #pragma unroll
    for (int nt = 0; nt < 7; ++nt) acc[nt] = (f32x4){0.f, 0.f, 0.f, 0.f};

    union FU { uint4 u; f16x8 h; };
    #pragma unroll
    for (int ks = 0; ks < 3; ++ks) {
        const int kb = ks * 16 + lg * 4;
        FU a, bfr[7];
        a.u = *reinterpret_cast<const uint4*>(gAu + (16 * w + lr) * KROW + kb);
        #pragma unroll
        for (int nt = 0; nt < 7; ++nt)
            bfr[nt].u = *reinterpret_cast<const uint4*>(W1b + (nt * 16 + lr) * KROW + kb);
        #pragma unroll
        for (int nt = 0; nt < 7; ++nt)
            acc[nt] = __builtin_amdgcn_mfma_f32_16x16x32_f16(a.h, bfr[nt].h, acc[nt], 0, 0, 0);
    }
    __syncthreads();   // staging dead; reuse LDS as f16 T

    _Float16* Th = (_Float16*)LDS;   // [128][TROW] f16 (26.6 KB)
    #pragma unroll
    for (int nt = 0; nt < 7; ++nt)
        #pragma unroll
        for (int r = 0; r < 4; ++r) {
            const int brow = 16 * w + lg * 4 + r;
            const int j    = nt * 16 + lr;
            if (j < NJ) Th[brow * TROW + j] = (_Float16)acc[nt][r];
        }
    __syncthreads();

    // part write: uint2 (4 f16) per op — 3200 per block, coalesced 8B runs
    const uint2* Tu = reinterpret_cast<const uint2*>(Th);    // row stride 26 uint2
    uint2* pu = reinterpret_cast<uint2*>(part);
    for (int idx = tid; idx < 128 * 25; idx += NT) {
        const int bl = idx / 25, jq = idx % 25;
        pu[((size_t)(bt * 128 + bl) * NMC + mc) * 25 + jq] = Tu[bl * 26 + jq];
    }
}

// ---- KC: reduce (f16 part) + fc2 + log_softmax; 512 threads (R25/R26) ----
__global__ __launch_bounds__(512)
void kc_out(const _Float16* __restrict__ part, const float* __restrict__ fb1,
            const float* __restrict__ W2,  const float* __restrict__ fb2,
            float* __restrict__ out)
{
    __shared__ _Float16 S[NMC * NJ];   // 19.2 KB
    __shared__ float a1s[NJ];
    __shared__ float a2[CLS];
    const int tid = threadIdx.x;
    const int b   = blockIdx.x;

    const uint4* src4 = reinterpret_cast<const uint4*>(part + (size_t)b * NMC * NJ);
    uint4* S4 = reinterpret_cast<uint4*>(S);
    for (int idx = tid; idx < (NMC * NJ) / 8; idx += 512) S4[idx] = src4[idx];
    __syncthreads();

    if (tid < NJ) {
        float s = fb1[tid];
        #pragma unroll 8
        for (int mc = 0; mc < NMC; ++mc) s += (float)S[mc * NJ + tid];
        a1s[tid] = fmaxf(s, 0.f);
    }
    __syncthreads();

    if (tid < CLS) {
        float acc = fb2[tid];
        #pragma unroll 4
        for (int j = 0; j < NJ; ++j) acc += a1s[j] * W2[tid * NJ + j];
        a2[tid] = acc;
    }
    __syncthreads();

    if (tid < CLS) {
        float mx = -INFINITY;
        #pragma unroll
        for (int n = 0; n < CLS; ++n) mx = fmaxf(mx, a2[n]);
        float s = 0.f;
        #pragma unroll
        for (int n = 0; n < CLS; ++n) s += expf(a2[n] - mx);
        out[b * CLS + tid] = a2[tid] - mx - logf(s);
    }
}

extern "C" void kernel_launch(void* const* d_in, const int* in_sizes, int n_in,
                              void* d_out, int out_size, void* d_ws, size_t ws_size,
                              hipStream_t stream)
{
    const float* x   = (const float*)d_in[0];
    const float* w1  = (const float*)d_in[1];
    const float* b1  = (const float*)d_in[2];
    const float* t1  = (const float*)d_in[3];
    const float* w2  = (const float*)d_in[4];
    const float* b2  = (const float*)d_in[5];
    const float* t2  = (const float*)d_in[6];
    const float* fw1 = (const float*)d_in[7];
    const float* fb1 = (const float*)d_in[8];
    const float* fw2 = (const float*)d_in[9];
    const float* fb2 = (const float*)d_in[10];

    _Float16* part = (_Float16*)d_ws;   // [256*96*100] f16 = 4.9 MB

    kb_fused<<<2 * NMC, NT, 0, stream>>>(x, w1, b1, t1, w2, b2, t2, fw1, part);
    kc_out  <<<256, 512, 0, stream>>>(part, fb1, fw2, fb2, (float*)d_out);
}